// Round 10
// baseline (297.397 us; speedup 1.0000x reference)
//
#include <hip/hip_runtime.h>

namespace {

typedef __attribute__((ext_vector_type(8))) short short8;
typedef __attribute__((ext_vector_type(16))) float f32x16;

constexpr int Hh = 32, Ssq = 4096, NCH = 64;
constexpr int GR = 2048;  // global row stride (floats) for X/B/C/Y
constexpr int ST = 72;    // LDS bf16 row stride: 144B, 16B-aligned rows (b128 frags)

__device__ inline unsigned short f2bf(float f) {
  unsigned u = __float_as_uint(f);
  u += 0x7FFFu + ((u >> 16) & 1u);  // RNE
  return (unsigned short)(u >> 16);
}
__device__ inline float bf2f(unsigned short s) {
  return __uint_as_float(((unsigned)s) << 16);
}

__device__ inline short8 pack8(float4 a, float4 b) {
  short8 o;
  o[0] = (short)f2bf(a.x); o[1] = (short)f2bf(a.y);
  o[2] = (short)f2bf(a.z); o[3] = (short)f2bf(a.w);
  o[4] = (short)f2bf(b.x); o[5] = (short)f2bf(b.y);
  o[6] = (short)f2bf(b.z); o[7] = (short)f2bf(b.w);
  return o;
}

// 32x32x16 bf16 MFMA operand: lane l -> row (l&31), k = ks*16 + (l>>5)*8 .. +8,
// from a row-major [row][k] LDS array (verified R9).
__device__ inline short8 frag128(const unsigned short* base, int row, int ks, int lhi) {
  return *(const short8*)(base + row * ST + ks * 16 + lhi * 8);
}
// Same fragment straight from a row-major fp32 global row pointer.
__device__ inline short8 gfrag(const float* rowp, int ks, int lhi) {
  const int off = ks * 16 + lhi * 8;
  float4 a = *(const float4*)(rowp + off);
  float4 b = *(const float4*)(rowp + off + 4);
  return pack8(a, b);
}

// ---------------- K1a: per-chunk LOCAL state (fully parallel) ---------------
// grid 8192 = (b,chunk,h); 256 threads (4 waves). sl_c = ea*(X^T.(iel*B)) as
// bf16 [p][n] -> ws slot c. Global loads hoisted above the A-scan.
__global__ __launch_bounds__(256, 6)
void k1a_chunkstate(const float* __restrict__ X0, const float* __restrict__ A0,
                    const float* __restrict__ B0, unsigned short* __restrict__ S16) {
  __shared__ __align__(16) unsigned short BTs[64 * ST];  // (iel*B)^T -> [n][l]
  __shared__ __align__(16) unsigned short XTs[64 * ST];  // X^T[p][l]
  __shared__ float ielb[64];
  __shared__ float eab;

  const int tid = threadIdx.x;
  const int hi = blockIdx.x & 31, ci = (blockIdx.x >> 5) & 63, bi = blockIdx.x >> 11;
  if (ci == 63) return;  // chunk 63's local state is never consumed

  const float* Xg = X0 + (((size_t)bi * Ssq + ci * 64) * Hh + hi) * 64;
  const float* Bg = B0 + (((size_t)bi * Ssq + ci * 64) * Hh + hi) * 64;
  const float* Ag = A0 + ((size_t)bi * Ssq + ci * 64) * Hh + hi;
  unsigned short* sp = S16 + ((size_t)(bi * Hh + hi) * NCH + ci) * 4096;

  const int w = tid >> 6, lane = tid & 63;
  const int l31 = lane & 31, lhi = lane >> 5;

  // issue all staged loads FIRST (latency hides under the scan)
  const int r = tid >> 2, cb = (tid & 3) * 4;
  float4 bv[4], xv[4];
#pragma unroll
  for (int j = 0; j < 4; ++j) {
    const int c = cb + 16 * j;
    bv[j] = *(const float4*)(Bg + (size_t)r * GR + c);
    xv[j] = *(const float4*)(Xg + (size_t)r * GR + c);
  }

  if (tid < 64) {  // A cumsum scan
    float a = Ag[(size_t)tid * Hh];
#pragma unroll
    for (int off = 1; off < 64; off <<= 1) {
      float v = __shfl_up(a, off);
      if (tid >= off) a += v;
    }
    ielb[tid] = __expf(-a);
    if (tid == 63) eab = __expf(a);
  }
  __syncthreads();

  {  // fold + cvt + scatter
    const float iel = ielb[r];
#pragma unroll
    for (int j = 0; j < 4; ++j) {
      const int c = cb + 16 * j;
      BTs[(c + 0) * ST + r] = f2bf(bv[j].x * iel);
      BTs[(c + 1) * ST + r] = f2bf(bv[j].y * iel);
      BTs[(c + 2) * ST + r] = f2bf(bv[j].z * iel);
      BTs[(c + 3) * ST + r] = f2bf(bv[j].w * iel);
      XTs[(c + 0) * ST + r] = f2bf(xv[j].x);
      XTs[(c + 1) * ST + r] = f2bf(xv[j].y);
      XTs[(c + 2) * ST + r] = f2bf(xv[j].z);
      XTs[(c + 3) * ST + r] = f2bf(xv[j].w);
    }
  }
  __syncthreads();

  const int tp = w >> 1, tn = w & 1;  // 32x32 output tile
  f32x16 acc = {};
#pragma unroll
  for (int ks = 0; ks < 4; ++ks)
    acc = __builtin_amdgcn_mfma_f32_32x32x16_bf16(
        frag128(XTs, 32 * tp + l31, ks, lhi),
        frag128(BTs, 32 * tn + l31, ks, lhi), acc, 0, 0, 0);
  const float ea = eab;
#pragma unroll
  for (int i = 0; i < 16; ++i) {
    const int p = 32 * tp + (i & 3) + 8 * (i >> 2) + 4 * lhi;
    sp[p * 64 + 32 * tn + l31] = f2bf(acc[i] * ea);
  }
}

// ---------------- K1b: inter-chunk scan (in-place, 4-deep prefetch) ---------
__global__ __launch_bounds__(256)
void k1b_scan(const float* __restrict__ A0, unsigned short* __restrict__ S16) {
  __shared__ float part[256];
  __shared__ float eat[64];

  const int tid = threadIdx.x;
  const int sl8 = blockIdx.x & 7, hi = (blockIdx.x >> 3) & 31, bi = blockIdx.x >> 8;
  const float* Ag = A0 + (size_t)bi * Ssq * Hh + hi;

  {  // per-chunk A totals
    const int c = tid >> 2, q = tid & 3;
    float s = 0.f;
#pragma unroll
    for (int k = 0; k < 16; ++k) s += Ag[(size_t)(c * 64 + q * 16 + k) * Hh];
    part[tid] = s;
  }
  __syncthreads();
  if (tid < 64)
    eat[tid] = __expf(part[tid * 4] + part[tid * 4 + 1] + part[tid * 4 + 2] + part[tid * 4 + 3]);
  __syncthreads();

  unsigned short* base =
      S16 + (size_t)(bi * Hh + hi) * NCH * 4096 + sl8 * 512 + tid * 2;
  float s0 = 0.f, s1 = 0.f;

  auto L = [&](int c) -> unsigned {
    return (c < 63) ? *(const unsigned*)(base + (size_t)c * 4096) : 0u;
  };
  auto step = [&](int c, unsigned v) {
    const float ea = eat[c];
    s0 = s0 * ea + bf2f((unsigned short)(v & 0xffffu));
    s1 = s1 * ea + bf2f((unsigned short)(v >> 16));
    *(unsigned*)(base + (size_t)(c + 1) * 4096) =
        (unsigned)f2bf(s0) | ((unsigned)f2bf(s1) << 16);
  };

  unsigned q0 = L(0), q1 = L(1), q2 = L(2), q3 = L(3);
  for (int c = 0; c < 60; c += 4) {
    step(c + 0, q0); q0 = L(c + 4);
    step(c + 1, q1); q1 = L(c + 5);
    step(c + 2, q2); q2 = L(c + 6);
    step(c + 3, q3); q3 = L(c + 7);
  }
  step(60, q0); step(61, q1); step(62, q2);
}

// ---------------- K2: per-chunk Y (fully parallel, 32x32 MFMA) --------------
// grid 8192 = (b,chunk,h); 256 threads (4 waves). LDS only Gs + XT (18.9 KB).
// C and B fragments load DIRECTLY from global (fp32 -> cvt); iel[s] fold moved
// to the G-epilogue as elb[grow]*ielb[gcol]. 2 barriers. Phase A: all 4 waves,
// tile (w>>1, w&1); the (0,1) tile masks to all-zero. Phase B: Y tile (w>>1,w&1).
__global__ __launch_bounds__(256, 6)
void k2_y(const float* __restrict__ X0, const float* __restrict__ A0,
          const float* __restrict__ B0, const float* __restrict__ C0,
          const unsigned short* __restrict__ S16, float* __restrict__ Y0) {
  __shared__ __align__(16) unsigned short Gs[64 * ST];  // G[l][s]
  __shared__ __align__(16) unsigned short XT[64 * ST];  // X^T[p][l]
  __shared__ float elb[64], ielb[64];

  const int tid = threadIdx.x;
  const int hi = blockIdx.x & 31, ci = (blockIdx.x >> 5) & 63, bi = blockIdx.x >> 11;

  const float* Xg = X0 + (((size_t)bi * Ssq + ci * 64) * Hh + hi) * 64;
  const float* Bg = B0 + (((size_t)bi * Ssq + ci * 64) * Hh + hi) * 64;
  const float* Cg = C0 + (((size_t)bi * Ssq + ci * 64) * Hh + hi) * 64;
  const float* Ag = A0 + ((size_t)bi * Ssq + ci * 64) * Hh + hi;
  const unsigned short* Sg = S16 + ((size_t)(bi * Hh + hi) * NCH + ci) * 4096;
  float* Yg = Y0 + (((size_t)bi * Ssq + ci * 64) * Hh + hi) * 64;

  const int w = tid >> 6, lane = tid & 63;
  const int l31 = lane & 31, lhi = lane >> 5;
  const int ti = w >> 1, tj = w & 1;  // tile coords for both phases

  // issue X staging loads + S_in fragment loads FIRST
  const int r = tid >> 2, cb = (tid & 3) * 4;
  float4 xv[4];
#pragma unroll
  for (int j = 0; j < 4; ++j)
    xv[j] = *(const float4*)(Xg + (size_t)r * GR + cb + 16 * j);

  short8 sf[4] = {};
  if (ci != 0) {
    const unsigned short* srow = Sg + (32 * tj + l31) * 64;
#pragma unroll
    for (int ks = 0; ks < 4; ++ks)
      sf[ks] = *(const short8*)(srow + ks * 16 + lhi * 8);
  }

  if (tid < 64) {  // A cumsum scan
    float a = Ag[(size_t)tid * Hh];
#pragma unroll
    for (int off = 1; off < 64; off <<= 1) {
      float v = __shfl_up(a, off);
      if (tid >= off) a += v;
    }
    elb[tid] = __expf(a);
    ielb[tid] = __expf(-a);
  }

  {  // scatter X^T
#pragma unroll
    for (int j = 0; j < 4; ++j) {
      const int c = cb + 16 * j;
      XT[(c + 0) * ST + r] = f2bf(xv[j].x);
      XT[(c + 1) * ST + r] = f2bf(xv[j].y);
      XT[(c + 2) * ST + r] = f2bf(xv[j].z);
      XT[(c + 3) * ST + r] = f2bf(xv[j].w);
    }
  }
  __syncthreads();  // B1: XT + exp tables ready

  {  // phase A: G tile (ti,tj) = tril(C.B^T)*exp(ac_l - ac_s); direct-global frags
    const float* crow = Cg + (size_t)(32 * ti + l31) * GR;
    const float* brow = Bg + (size_t)(32 * tj + l31) * GR;
    short8 af[4], bf[4];
#pragma unroll
    for (int ks = 0; ks < 4; ++ks) {
      af[ks] = gfrag(crow, ks, lhi);
      bf[ks] = gfrag(brow, ks, lhi);
    }
    f32x16 ga = {};
#pragma unroll
    for (int ks = 0; ks < 4; ++ks)
      ga = __builtin_amdgcn_mfma_f32_32x32x16_bf16(af[ks], bf[ks], ga, 0, 0, 0);

    const int gcol = 32 * tj + l31;
    const float ielc = ielb[gcol];
#pragma unroll
    for (int i = 0; i < 16; ++i) {
      const int grow = 32 * ti + (i & 3) + 8 * (i >> 2) + 4 * lhi;
      float gv = (gcol <= grow) ? ga[i] * (elb[grow] * ielc) : 0.f;
      Gs[grow * ST + gcol] = f2bf(gv);
    }
  }
  __syncthreads();  // B2: G ready

  {  // phase B: Y tile (ti,tj) = G.X + el*(C.S^T)
    const float* crow = Cg + (size_t)(32 * ti + l31) * GR;
    short8 cf[4];
#pragma unroll
    for (int ks = 0; ks < 4; ++ks) cf[ks] = gfrag(crow, ks, lhi);

    f32x16 aD = {}, aO = {};
#pragma unroll
    for (int ks = 0; ks < 4; ++ks)
      aD = __builtin_amdgcn_mfma_f32_32x32x16_bf16(
          frag128(Gs, 32 * ti + l31, ks, lhi),
          frag128(XT, 32 * tj + l31, ks, lhi), aD, 0, 0, 0);
    if (ci != 0) {
#pragma unroll
      for (int ks = 0; ks < 4; ++ks)
        aO = __builtin_amdgcn_mfma_f32_32x32x16_bf16(cf[ks], sf[ks], aO, 0, 0, 0);
    }
#pragma unroll
    for (int i = 0; i < 16; ++i) {
      const int row = 32 * ti + (i & 3) + 8 * (i >> 2) + 4 * lhi;
      Yg[(size_t)row * GR + 32 * tj + l31] = aD[i] + elb[row] * aO[i];
    }
  }
}

}  // namespace

extern "C" void kernel_launch(void* const* d_in, const int* in_sizes, int n_in,
                              void* d_out, int out_size, void* d_ws, size_t ws_size,
                              hipStream_t stream) {
  const float* X = (const float*)d_in[0];
  const float* A = (const float*)d_in[1];
  const float* B = (const float*)d_in[2];
  const float* C = (const float*)d_in[3];
  float* Y = (float*)d_out;
  unsigned short* S16 = (unsigned short*)d_ws;  // 4*32*64*4096*2 = 67 MB
  (void)in_sizes; (void)n_in; (void)out_size; (void)ws_size;
  k1a_chunkstate<<<dim3(8192), dim3(256), 0, stream>>>(X, A, B, S16);
  k1b_scan<<<dim3(1024), dim3(256), 0, stream>>>(A, S16);
  k2_y<<<dim3(8192), dim3(256), 0, stream>>>(X, A, B, C, S16, Y);
}